// Round 3
// baseline (1176.836 us; speedup 1.0000x reference)
//
#include <hip/hip_runtime.h>

// Llama4TextExperts: E=8, H=2048, D=2048, 4096 tokens/expert.
// out = (up * silu(gate)) @ W2,  [gate|up] = x @ W1
// Round 3: 8-phase 256x256 GEMM with sched_barrier-pinned phases, balanced
// ds_read bursts (B-qn0 prefetched in P4), P4 barrier removed, vmcnt after
// P4 MFMA. SwiGLU fused via gate/up 16-col interleaved B-row remap.

#define E_EXPERTS 8
#define TPE 4096
#define KD 2048

typedef __bf16 bf16_t;
typedef __bf16 bf16x4 __attribute__((ext_vector_type(4)));
typedef __bf16 bf16x8 __attribute__((ext_vector_type(8)));
typedef float f32x4 __attribute__((ext_vector_type(4)));

#define GLOAD16(src, dst)                                               \
  __builtin_amdgcn_global_load_lds(                                     \
      (const __attribute__((address_space(1))) void*)(src),             \
      (__attribute__((address_space(3))) void*)(dst), 16, 0, 0)

// ---------------- pass 1: x f32 -> bf16 ----------------
__global__ void cvt_f32_bf16_kernel(const float* __restrict__ in,
                                    bf16_t* __restrict__ out, long n4) {
  long i = (long)blockIdx.x * blockDim.x + threadIdx.x;
  const long stride = (long)gridDim.x * blockDim.x;
  const float4* in4 = (const float4*)in;
  bf16x4* out4 = (bf16x4*)out;
  for (; i < n4; i += stride) {
    float4 v = in4[i];
    bf16x4 o = {(bf16_t)v.x, (bf16_t)v.y, (bf16_t)v.z, (bf16_t)v.w};
    out4[i] = o;
  }
}

// ------- pass 2: per-expert transpose+convert: W[K][N] f32 -> WT[N][K] bf16 -------
__global__ void transpose_cvt_kernel(const float* __restrict__ W,
                                     bf16_t* __restrict__ WT, int K, int N) {
  __shared__ float tile[64][65];
  const int e = blockIdx.z;
  const float* Wp = W + (size_t)e * K * N;
  bf16_t* Tp = WT + (size_t)e * N * K;
  const int n0 = blockIdx.x * 64, k0 = blockIdx.y * 64;
  const int rr = threadIdx.x >> 4;
  const int cc = (threadIdx.x & 15) * 4;
#pragma unroll
  for (int p = 0; p < 4; ++p) {
    const int k = rr + p * 16;
    float4 v = *(const float4*)(Wp + (size_t)(k0 + k) * N + n0 + cc);
    tile[k][cc + 0] = v.x;
    tile[k][cc + 1] = v.y;
    tile[k][cc + 2] = v.z;
    tile[k][cc + 3] = v.w;
  }
  __syncthreads();
#pragma unroll
  for (int p = 0; p < 4; ++p) {
    const int n = rr + p * 16;
    bf16x4 o;
#pragma unroll
    for (int j = 0; j < 4; ++j) o[j] = (bf16_t)tile[cc + j][n];
    *(bf16x4*)(Tp + (size_t)(n0 + n) * K + k0 + cc) = o;
  }
}

// ---------------- 256x256 8-phase grouped GEMM ----------------
// Per K-tile t (buf=t&1), phases (per wave, output quadrants of its 128x64):
//  P1: readA(qm0)[8]; stage (t+1).Ah0->buf^1 | BAR lgkm0 sched0 | MFMA(0,0,b0) | BAR
//  P2: readB(qn1)[4]; stage (t+1).Ah1->buf^1 | BAR lgkm0 sched0 | MFMA(0,1,b1) | BAR
//  P3: readA(qm1)[8]; stage (t+2).Bh0->buf   | BAR lgkm0 sched0 | MFMA(1,1,b1) | BAR
//  P4: stage (t+2).Bh1->buf | MFMA(1,0,b0) | vmcnt(4) | readB(buf^1,qn0)->b0 | BAR
// b0 for tile t is prefetched at (t-1).P4 (post-vmcnt: t.B provably landed).
// Race-safety: A->buf^1 legal any phase (t-1 A-reads done at t-1.P3-end BAR);
// B(t+2)->buf legal from P3 (B-reads of buf done: qn0 at t-1.P4, qn1 at t.P2,
// both before t.P2-end BAR). vmcnt(4) survivors are exactly (t+2).B.
#define MMA_QUAD(QM, QN, BF)                                                 \
  do {                                                                       \
    _Pragma("unroll") for (int kk = 0; kk < 2; ++kk) {                       \
      _Pragma("unroll") for (int m = 0; m < 4; ++m) {                        \
        _Pragma("unroll") for (int n = 0; n < 2; ++n) {                      \
          acc[(QM)*4 + m][(QN)*2 + n] =                                      \
              __builtin_amdgcn_mfma_f32_16x16x32_bf16(                       \
                  af[m][kk], BF[n][kk], acc[(QM)*4 + m][(QN)*2 + n], 0, 0, 0); \
        }                                                                    \
      }                                                                      \
    }                                                                        \
  } while (0)

template <bool FUSED, int NTN>
__global__ __launch_bounds__(512, 2) void moe_gemm8_kernel(
    const bf16_t* __restrict__ A, const bf16_t* __restrict__ Bm,
    void* __restrict__ Cout) {
  constexpr int NT = KD / 64;  // 32 K-tiles
  constexpr int NWG = E_EXPERTS * 16 * NTN;

  __shared__ alignas(16) bf16_t As[2][256][64];
  __shared__ alignas(16) bf16_t Bs[2][256][64];

  // bijective XCD swizzle (NWG % 8 == 0); each XCD owns exactly one expert.
  int wg = blockIdx.x;
  wg = (wg & 7) * (NWG / 8) + (wg >> 3);
  const int e = wg / (16 * NTN);
  const int rem = wg % (16 * NTN);
  const int mt = rem / NTN, ntile = rem % NTN;
  const int t0 = mt * 256, n0 = ntile * 256;

  const int tid = threadIdx.x;
  const int wid = tid >> 6, lane = tid & 63;
  const int wr = wid >> 2, wc = wid & 3;  // 2(M) x 4(N) waves; 128x64 each

  const bf16_t* Ae = A + (size_t)e * TPE * KD + (size_t)t0 * KD;
  const bf16_t* Be = Bm + (size_t)e * (size_t)(FUSED ? 4096 : 2048) * KD;

  const int slr = lane >> 3;               // row 0..7 in 8-row block
  const int sel = ((lane & 7) ^ slr) * 8;  // pre-swizzled source chunk

  auto stageA = [&](int kt, int h) {
    const int ktw = kt & (NT - 1);
    const int k0 = ktw * 64;
    const int buf = kt & 1;
#pragma unroll
    for (int i = 0; i < 2; ++i) {
      const int r0 = h * 128 + wid * 16 + i * 8;
      GLOAD16(Ae + (size_t)(r0 + slr) * KD + k0 + sel, &As[buf][r0][0]);
    }
  };
  auto stageB = [&](int kt, int h) {
    const int ktw = kt & (NT - 1);
    const int k0 = ktw * 64;
    const int buf = kt & 1;
#pragma unroll
    for (int i = 0; i < 2; ++i) {
      const int r0 = h * 128 + wid * 16 + i * 8;
      const int R = n0 + r0 + slr;
      int srow;
      if constexpr (FUSED)
        srow = ((R >> 5) << 4) + (R & 15) + ((R >> 4) & 1) * 2048;
      else
        srow = R;
      GLOAD16(Be + (size_t)srow * KD + k0 + sel, &Bs[buf][r0][0]);
    }
  };

  const int la = lane & 15, kg4 = lane >> 4;

  f32x4 acc[8][4] = {};
  bf16x8 af[4][2];
  bf16x8 b0[2][2];
  bf16x8 b1[2][2];

  auto readA = [&](int buf, int qm) {
#pragma unroll
    for (int m = 0; m < 4; ++m) {
      const int row = wr * 128 + qm * 64 + m * 16 + la;
#pragma unroll
      for (int kk = 0; kk < 2; ++kk) {
        const int ch = ((kk * 4 + kg4) ^ (la & 7)) * 8;
        af[m][kk] = *(const bf16x8*)&As[buf][row][ch];
      }
    }
  };
  auto readB = [&](int buf, int qn, bf16x8 (&bf)[2][2]) {
#pragma unroll
    for (int n = 0; n < 2; ++n) {
      const int row = wc * 64 + qn * 32 + n * 16 + la;
#pragma unroll
      for (int kk = 0; kk < 2; ++kk) {
        const int ch = ((kk * 4 + kg4) ^ (la & 7)) * 8;
        bf[n][kk] = *(const bf16x8*)&Bs[buf][row][ch];
      }
    }
  };

#define LGKM0 asm volatile("s_waitcnt lgkmcnt(0)" ::: "memory")
#define VMC4 asm volatile("s_waitcnt vmcnt(4)" ::: "memory")
#define BAR __builtin_amdgcn_s_barrier()
#define SCHED0 __builtin_amdgcn_sched_barrier(0)
#define PRIO1 __builtin_amdgcn_s_setprio(1)
#define PRIO0 __builtin_amdgcn_s_setprio(0)

  // prologue: tile0 full + tile1 B; drain to 4 (tile1.B stays in flight)
  stageA(0, 0); stageA(0, 1);
  stageB(0, 0); stageB(0, 1);
  stageB(1, 0); stageB(1, 1);
  VMC4;
  BAR;
  readB(0, 0, b0);  // tile0 qn0 prefetch (P1's lgkm0 covers it)

  auto tile = [&](int kt, int buf) {
    // P1
    readA(buf, 0);
    stageA(kt + 1, 0);
    BAR; LGKM0; SCHED0;
    PRIO1; MMA_QUAD(0, 0, b0); PRIO0;
    BAR;
    // P2
    readB(buf, 1, b1);
    stageA(kt + 1, 1);
    BAR; LGKM0; SCHED0;
    PRIO1; MMA_QUAD(0, 1, b1); PRIO0;
    BAR;
    // P3
    readA(buf, 1);
    stageB(kt + 2, 0);
    BAR; LGKM0; SCHED0;
    PRIO1; MMA_QUAD(1, 1, b1); PRIO0;
    BAR;
    // P4 (register-only MFMA; no pre-barrier)
    stageB(kt + 2, 1);
    PRIO1; MMA_QUAD(1, 0, b0); PRIO0;
    VMC4;
    readB(buf ^ 1, 0, b0);  // next tile's qn0 (data landed by VMC4)
    BAR;
  };

  for (int kt = 0; kt < NT; kt += 2) {
    tile(kt, 0);
    tile(kt + 1, 1);
  }

  // Epilogue. C/D layout: row=(lane>>4)*4+r, col=lane&15 (verified).
  const int lg = lane >> 4;
  const int rbase = t0 + wr * 128;
  if constexpr (FUSED) {
    bf16_t* Cp = (bf16_t*)Cout + (size_t)e * TPE * KD;
    const int jb = (n0 + wc * 64) >> 1;  // even frag=gate, odd=up
#pragma unroll
    for (int m = 0; m < 8; ++m)
#pragma unroll
      for (int p = 0; p < 2; ++p)
#pragma unroll
        for (int r = 0; r < 4; ++r) {
          const int row = rbase + m * 16 + lg * 4 + r;
          const int col = jb + p * 16 + la;
          const float g = acc[m][2 * p][r], u = acc[m][2 * p + 1][r];
          const float s = 1.0f / (1.0f + __expf(-g));
          Cp[(size_t)row * KD + col] = (bf16_t)(u * g * s);
        }
  } else {
    float* Cp = (float*)Cout + (size_t)e * TPE * KD;
#pragma unroll
    for (int m = 0; m < 8; ++m)
#pragma unroll
      for (int n = 0; n < 4; ++n)
#pragma unroll
        for (int r = 0; r < 4; ++r) {
          const int row = rbase + m * 16 + lg * 4 + r;
          const int col = n0 + wc * 64 + n * 16 + la;
          Cp[(size_t)row * KD + col] = acc[m][n][r];
        }
  }
#undef LGKM0
#undef VMC4
#undef BAR
#undef SCHED0
#undef PRIO1
#undef PRIO0
}

extern "C" void kernel_launch(void* const* d_in, const int* in_sizes, int n_in,
                              void* d_out, int out_size, void* d_ws,
                              size_t ws_size, hipStream_t stream) {
  const float* hs = (const float*)d_in[0];  // (32768, 2048)
  const float* w1 = (const float*)d_in[1];  // (8, 2048, 4096)
  const float* w2 = (const float*)d_in[2];  // (8, 2048, 2048)

  // ws layout (448 MiB):
  //   xb  bf16 [32768][2048]     128 MiB @ 0
  //   w1t bf16 [8][4096][2048]   128 MiB @ 128M
  //   w2t bf16 [8][2048][2048]    64 MiB @ 256M
  //   act bf16 [8][4096][2048]   128 MiB @ 320M
  char* ws = (char*)d_ws;
  bf16_t* xb = (bf16_t*)(ws);
  bf16_t* w1t = (bf16_t*)(ws + (size_t)134217728);
  bf16_t* w2t = (bf16_t*)(ws + (size_t)268435456);
  bf16_t* act = (bf16_t*)(ws + (size_t)335544320);

  const long n4 = (long)E_EXPERTS * TPE * KD / 4;
  cvt_f32_bf16_kernel<<<2048, 256, 0, stream>>>(hs, xb, n4);
  transpose_cvt_kernel<<<dim3(64, 32, 8), 256, 0, stream>>>(w1, w1t, 2048, 4096);
  transpose_cvt_kernel<<<dim3(32, 32, 8), 256, 0, stream>>>(w2, w2t, 2048, 2048);
  moe_gemm8_kernel<true, 16><<<2048, 512, 0, stream>>>(xb, w1t, (void*)act);
  moe_gemm8_kernel<false, 8><<<1024, 512, 0, stream>>>(act, w2t, d_out);
}

// Round 4
// 1114.931 us; speedup vs baseline: 1.0555x; 1.0555x over previous
//
#include <hip/hip_runtime.h>

// Llama4TextExperts: E=8, H=2048, D=2048, 4096 tokens/expert.
// out = (up * silu(gate)) @ W2,  [gate|up] = x @ W1
// Round 4: half-phase (8x per K-tile) rolling pipeline with COUNTED lgkmcnt
// waits — ds_reads issued >=2 half-phases ahead of their MFMA cluster so the
// LDS drain hides under MFMA. A-fragment ping-pong (register-neutral), B
// buffers role-flip per K-tile. 4 barriers/K-tile. vmcnt(4) once per K-tile.

#define E_EXPERTS 8
#define TPE 4096
#define KD 2048

typedef __bf16 bf16_t;
typedef __bf16 bf16x4 __attribute__((ext_vector_type(4)));
typedef __bf16 bf16x8 __attribute__((ext_vector_type(8)));
typedef float f32x4 __attribute__((ext_vector_type(4)));

#define GLOAD16(src, dst)                                               \
  __builtin_amdgcn_global_load_lds(                                     \
      (const __attribute__((address_space(1))) void*)(src),             \
      (__attribute__((address_space(3))) void*)(dst), 16, 0, 0)

// ---------------- pass 1: x f32 -> bf16 ----------------
__global__ void cvt_f32_bf16_kernel(const float* __restrict__ in,
                                    bf16_t* __restrict__ out, long n4) {
  long i = (long)blockIdx.x * blockDim.x + threadIdx.x;
  const long stride = (long)gridDim.x * blockDim.x;
  const float4* in4 = (const float4*)in;
  bf16x4* out4 = (bf16x4*)out;
  for (; i < n4; i += stride) {
    float4 v = in4[i];
    bf16x4 o = {(bf16_t)v.x, (bf16_t)v.y, (bf16_t)v.z, (bf16_t)v.w};
    out4[i] = o;
  }
}

// ------- pass 2: per-expert transpose+convert: W[K][N] f32 -> WT[N][K] bf16 -------
__global__ void transpose_cvt_kernel(const float* __restrict__ W,
                                     bf16_t* __restrict__ WT, int K, int N) {
  __shared__ float tile[64][65];
  const int e = blockIdx.z;
  const float* Wp = W + (size_t)e * K * N;
  bf16_t* Tp = WT + (size_t)e * N * K;
  const int n0 = blockIdx.x * 64, k0 = blockIdx.y * 64;
  const int rr = threadIdx.x >> 4;
  const int cc = (threadIdx.x & 15) * 4;
#pragma unroll
  for (int p = 0; p < 4; ++p) {
    const int k = rr + p * 16;
    float4 v = *(const float4*)(Wp + (size_t)(k0 + k) * N + n0 + cc);
    tile[k][cc + 0] = v.x;
    tile[k][cc + 1] = v.y;
    tile[k][cc + 2] = v.z;
    tile[k][cc + 3] = v.w;
  }
  __syncthreads();
#pragma unroll
  for (int p = 0; p < 4; ++p) {
    const int n = rr + p * 16;
    bf16x4 o;
#pragma unroll
    for (int j = 0; j < 4; ++j) o[j] = (bf16_t)tile[cc + j][n];
    *(bf16x4*)(Tp + (size_t)(n0 + n) * K + k0 + cc) = o;
  }
}

// ---------------- 256x256 half-phase-pipelined grouped GEMM ----------------
// Per K-tile t (buf=t&1), 8 half-phases H1..H8, zigzag order so each A-half
// buffer (afP/afQ ping-pong) has its two uses adjacent:
//   H1 m01*b0  H2 m01*b1 | H3 m23*b1  H4 m23*b0 |
//   H5 m45*b0  H6 m45*b1 | H7 m67*b1  H8 m67*b0
// ds_reads issued ~2 half-phases ahead; counted lgkm waits (audit in TILE).
// B phys buffers role-flip per tile: H8 (post-vmcnt) reads b0(t+1) into the
// buffer that held b1(t). Barriers at H2/H4/H6/H8 ends only.
// Safety: stageA(t+1)->As[buf^1]: readers (tile t-1 af reads) drained by
//   H7(t-1)'s W(0), sealed by H8(t-1) BAR. stageB(t+2)->Bs[buf] at H5/H7:
//   readers (b1@H1 drained by H2's W(4); b0 drained by H1's W(8)) sealed by
//   H4 BAR. vmcnt(4)@H8 leaves exactly B(t+2) in flight => A(t+1),B(t+1)
//   landed before H8's reads of tile t+1 fragments.
#define MMA_H(MP, AF, BF, QN)                                                \
  do {                                                                       \
    _Pragma("unroll") for (int kk = 0; kk < 2; ++kk) {                       \
      _Pragma("unroll") for (int mm = 0; mm < 2; ++mm) {                     \
        _Pragma("unroll") for (int n = 0; n < 2; ++n) {                      \
          acc[(MP)*2 + mm][(QN)*2 + n] =                                     \
              __builtin_amdgcn_mfma_f32_16x16x32_bf16(                       \
                  AF[mm][kk], BF[n][kk], acc[(MP)*2 + mm][(QN)*2 + n], 0, 0, \
                  0);                                                        \
        }                                                                    \
      }                                                                      \
    }                                                                        \
  } while (0)

template <bool FUSED, int NTN>
__global__ __launch_bounds__(512, 2) void moe_gemm8_kernel(
    const bf16_t* __restrict__ A, const bf16_t* __restrict__ Bm,
    void* __restrict__ Cout) {
  constexpr int NT = KD / 64;  // 32 K-tiles

  __shared__ alignas(16) bf16_t As[2][256][64];
  __shared__ alignas(16) bf16_t Bs[2][256][64];

  // bijective XCD swizzle (grid % 8 == 0); one expert per XCD.
  const int NWG = gridDim.x;
  int wg = blockIdx.x;
  wg = (wg & 7) * (NWG >> 3) + (wg >> 3);
  const int e = wg / (16 * NTN);
  const int rem = wg % (16 * NTN);
  const int mt = rem / NTN, ntile = rem % NTN;
  const int t0 = mt * 256, n0 = ntile * 256;

  const int tid = threadIdx.x;
  const int wid = tid >> 6, lane = tid & 63;
  const int wr = wid >> 2, wc = wid & 3;  // 2(M) x 4(N) waves; 128x64 each

  const bf16_t* Ae = A + (size_t)e * TPE * KD + (size_t)t0 * KD;
  const bf16_t* Be = Bm + (size_t)e * (size_t)(FUSED ? 4096 : 2048) * KD;

  const int slr = lane >> 3;               // row 0..7 in 8-row block
  const int sel = ((lane & 7) ^ slr) * 8;  // pre-swizzled source chunk

  auto stageA = [&](int kt, int h) {
    const int ktw = kt & (NT - 1);
    const int k0 = ktw * 64;
    const int buf = kt & 1;
#pragma unroll
    for (int i = 0; i < 2; ++i) {
      const int r0 = h * 128 + wid * 16 + i * 8;
      GLOAD16(Ae + (size_t)(r0 + slr) * KD + k0 + sel, &As[buf][r0][0]);
    }
  };
  auto stageB = [&](int kt, int h) {
    const int ktw = kt & (NT - 1);
    const int k0 = ktw * 64;
    const int buf = kt & 1;
#pragma unroll
    for (int i = 0; i < 2; ++i) {
      const int r0 = h * 128 + wid * 16 + i * 8;
      const int R = n0 + r0 + slr;
      int srow;
      if constexpr (FUSED)
        srow = ((R >> 5) << 4) + (R & 15) + ((R >> 4) & 1) * 2048;
      else
        srow = R;
      GLOAD16(Be + (size_t)srow * KD + k0 + sel, &Bs[buf][r0][0]);
    }
  };

  const int la = lane & 15, kg4 = lane >> 4;

  f32x4 acc[8][4] = {};
  bf16x8 afP[2][2], afQ[2][2];  // A m-pair ping-pong
  bf16x8 bA[2][2], bB[2][2];    // B buffers, role-flip per tile

  // read one A m-pair (4 x ds_read_b128)
  auto readAh = [&](int buf, int mp, bf16x8 (&dst)[2][2]) {
#pragma unroll
    for (int mm = 0; mm < 2; ++mm) {
      const int row = wr * 128 + mp * 32 + mm * 16 + la;
#pragma unroll
      for (int kk = 0; kk < 2; ++kk) {
        const int ch = ((kk * 4 + kg4) ^ (la & 7)) * 8;
        dst[mm][kk] = *(const bf16x8*)&As[buf][row][ch];
      }
    }
  };
  // read one B n-pair (4 x ds_read_b128)
  auto readBh = [&](int buf, int qn, bf16x8 (&dst)[2][2]) {
#pragma unroll
    for (int n = 0; n < 2; ++n) {
      const int row = wc * 64 + qn * 32 + n * 16 + la;
#pragma unroll
      for (int kk = 0; kk < 2; ++kk) {
        const int ch = ((kk * 4 + kg4) ^ (la & 7)) * 8;
        dst[n][kk] = *(const bf16x8*)&Bs[buf][row][ch];
      }
    }
  };

#define W8 asm volatile("s_waitcnt lgkmcnt(8)" ::: "memory")
#define W4 asm volatile("s_waitcnt lgkmcnt(4)" ::: "memory")
#define W0 asm volatile("s_waitcnt lgkmcnt(0)" ::: "memory")
#define VMC4 asm volatile("s_waitcnt vmcnt(4)" ::: "memory")
#define BAR __builtin_amdgcn_s_barrier()
#define SCHED0 __builtin_amdgcn_sched_barrier(0)
#define PRIO1 __builtin_amdgcn_s_setprio(1)
#define PRIO0 __builtin_amdgcn_s_setprio(0)

  // TILE(kt, buf, BX, BY): BX holds b0(kt) (read at prev H8); BY is free.
  // lgkm audit (this wave, in-order DS returns):
  //  enter: [m01(4), b0(4)] = 8
  //  H1: +b1(4)+m23(4)=16; W8 drains m01,b0. MFMA m01*b0.
  //  H2: W4 drains b1 (keeps m23). MFMA m01*b1. BAR.
  //  H3: +m45(4)=8; W4 drains m23. MFMA m23*b1.
  //  H4: (no wait). MFMA m23*b0. BAR.
  //  H5: +m67(4)=8; W4 drains m45. MFMA m45*b0.
  //  H6: (no wait). MFMA m45*b1. BAR.
  //  H7: W0 drains m67. MFMA m67*b1.
  //  H8: VMC4 (keeps B(kt+2) only); +m01'(4)+b0'(4)->BY. MFMA m67*b0. BAR.
#define TILE(kt, buf, BX, BY)                          \
  do {                                                 \
    /* H1 */                                           \
    readBh(buf, 1, BY);                                \
    readAh(buf, 1, afQ);                               \
    stageA((kt) + 1, 0);                               \
    W8; SCHED0;                                        \
    PRIO1; MMA_H(0, afP, BX, 0); PRIO0;                \
    /* H2 */                                           \
    W4; SCHED0;                                        \
    PRIO1; MMA_H(0, afP, BY, 1); PRIO0;                \
    BAR;                                               \
    /* H3 */                                           \
    readAh(buf, 2, afP);                               \
    stageA((kt) + 1, 1);                               \
    W4; SCHED0;                                        \
    PRIO1; MMA_H(1, afQ, BY, 1); PRIO0;                \
    /* H4 */                                           \
    PRIO1; MMA_H(1, afQ, BX, 0); PRIO0;                \
    BAR;                                               \
    /* H5 */                                           \
    readAh(buf, 3, afQ);                               \
    stageB((kt) + 2, 0);                               \
    W4; SCHED0;                                        \
    PRIO1; MMA_H(2, afP, BX, 0); PRIO0;                \
    /* H6 */                                           \
    PRIO1; MMA_H(2, afP, BY, 1); PRIO0;                \
    BAR;                                               \
    /* H7 */                                           \
    stageB((kt) + 2, 1);                               \
    W0; SCHED0;                                        \
    PRIO1; MMA_H(3, afQ, BY, 1); PRIO0;                \
    /* H8 */                                           \
    VMC4;                                              \
    readAh((buf) ^ 1, 0, afP);                         \
    readBh((buf) ^ 1, 0, BY);                          \
    PRIO1; MMA_H(3, afQ, BX, 0); PRIO0;                \
    BAR;                                               \
  } while (0)

  // prologue: tile0 A+B, tile1 B; drain to 4 (tile1.B in flight); first frags
  stageA(0, 0); stageA(0, 1);
  stageB(0, 0); stageB(0, 1);
  stageB(1, 0); stageB(1, 1);
  VMC4;
  BAR;
  readAh(0, 0, afP);   // m01(0)
  readBh(0, 0, bA);    // b0(0)

  for (int kt = 0; kt < NT; kt += 2) {
    TILE(kt, 0, bA, bB);
    TILE(kt + 1, 1, bB, bA);
  }

  // Epilogue. C/D layout: row=(lane>>4)*4+r, col=lane&15 (verified).
  const int lg = lane >> 4;
  const int rbase = t0 + wr * 128;
  if constexpr (FUSED) {
    bf16_t* Cp = (bf16_t*)Cout + (size_t)e * TPE * KD;
    const int jb = (n0 + wc * 64) >> 1;  // even frag=gate, odd=up
#pragma unroll
    for (int m = 0; m < 8; ++m)
#pragma unroll
      for (int p = 0; p < 2; ++p)
#pragma unroll
        for (int r = 0; r < 4; ++r) {
          const int row = rbase + m * 16 + lg * 4 + r;
          const int col = jb + p * 16 + la;
          const float g = acc[m][2 * p][r], u = acc[m][2 * p + 1][r];
          const float s = 1.0f / (1.0f + __expf(-g));
          Cp[(size_t)row * KD + col] = (bf16_t)(u * g * s);
        }
  } else {
    float* Cp = (float*)Cout + (size_t)e * TPE * KD;
#pragma unroll
    for (int m = 0; m < 8; ++m)
#pragma unroll
      for (int n = 0; n < 4; ++n)
#pragma unroll
        for (int r = 0; r < 4; ++r) {
          const int row = rbase + m * 16 + lg * 4 + r;
          const int col = n0 + wc * 64 + n * 16 + la;
          Cp[(size_t)row * KD + col] = acc[m][n][r];
        }
  }
#undef W8
#undef W4
#undef W0
#undef VMC4
#undef BAR
#undef SCHED0
#undef PRIO1
#undef PRIO0
}

extern "C" void kernel_launch(void* const* d_in, const int* in_sizes, int n_in,
                              void* d_out, int out_size, void* d_ws,
                              size_t ws_size, hipStream_t stream) {
  const float* hs = (const float*)d_in[0];  // (32768, 2048)
  const float* w1 = (const float*)d_in[1];  // (8, 2048, 4096)
  const float* w2 = (const float*)d_in[2];  // (8, 2048, 2048)

  // ws layout (448 MiB):
  //   xb  bf16 [32768][2048]     128 MiB @ 0
  //   w1t bf16 [8][4096][2048]   128 MiB @ 128M
  //   w2t bf16 [8][2048][2048]    64 MiB @ 256M
  //   act bf16 [8][4096][2048]   128 MiB @ 320M
  char* ws = (char*)d_ws;
  bf16_t* xb = (bf16_t*)(ws);
  bf16_t* w1t = (bf16_t*)(ws + (size_t)134217728);
  bf16_t* w2t = (bf16_t*)(ws + (size_t)268435456);
  bf16_t* act = (bf16_t*)(ws + (size_t)335544320);

  const long n4 = (long)E_EXPERTS * TPE * KD / 4;
  cvt_f32_bf16_kernel<<<2048, 256, 0, stream>>>(hs, xb, n4);
  transpose_cvt_kernel<<<dim3(64, 32, 8), 256, 0, stream>>>(w1, w1t, 2048, 4096);
  transpose_cvt_kernel<<<dim3(32, 32, 8), 256, 0, stream>>>(w2, w2t, 2048, 2048);
  moe_gemm8_kernel<true, 16><<<2048, 512, 0, stream>>>(xb, w1t, (void*)act);
  moe_gemm8_kernel<false, 8><<<1024, 512, 0, stream>>>(act, w2t, d_out);
}